// Round 9
// baseline (126.607 us; speedup 1.0000x reference)
//
#include <hip/hip_runtime.h>
#include <math.h>

#define N_ROWS 8192
#define D 16
#define TILE 128
#define NT 64            /* 8192/128 */
#define NBLK 2080        /* NT*(NT+1)/2 upper-tri tiles = 32*65 */

/* workspace layout (bytes) */
#define OFF_PT   0            /* float pt[2080]      (real) */
#define OFF_PS   16384        /* float ps[2080]      (real) */
#define OFF_PTA  32768        /* float ptA[2080*4]   (diag FULL) */
#define OFF_PSA  98304        /* float psA[2080*4]   */
#define OFF_PTB  163840       /* float ptB[2080*6]   (diag NOEPI) */
#define OFF_PSB  229376       /* float psB[2080*6]   */

typedef short  bf16x8 __attribute__((ext_vector_type(8)));
typedef float  f32x4  __attribute__((ext_vector_type(4)));

#if __has_builtin(__builtin_amdgcn_sqrtf)
#define SQRTF(x) __builtin_amdgcn_sqrtf(x)
#else
#define SQRTF(x) sqrtf(x)
#endif

/* codon index -> biosynthetic family id (K resolves to aspartate; '*' -> -1)
   families: 0=glutamate 1=aspartate 2=serine 3=pyruvate 4=aromatic 5=histidine */
__device__ __constant__ signed char FAM_LUT[64] = {
  4,4,3,3, 3,3,3,3,   /* UUU..CUG: F F L L L L L L */
  1,1,1,1, 3,3,3,3,   /* AUU..GUG: I I I M V V V V */
  2,2,2,2, 0,0,0,0,   /* UCU..CCG: S S S S P P P P */
  1,1,1,1, 3,3,3,3,   /* ACU..GCG: T T T T A A A A */
  4,4,-1,-1, 5,5,0,0, /* UAU..CAG: Y Y * * H H Q Q */
  1,1,1,1, 1,1,0,0,   /* AAU..GAG: N N K K D D E E */
  2,2,-1,4, 0,0,0,0,  /* UGU..CGG: C C * W R R R R */
  2,2,0,0, 2,2,2,2    /* AGU..GGG: S S R R G G G G */
};

__device__ __forceinline__ unsigned short f2bf(float f) {   /* RNE, finite inputs */
  unsigned u = __float_as_uint(f);
  u += 0x7fffu + ((u >> 16) & 1u);
  return (unsigned short)(u >> 16);
}
__device__ __forceinline__ float bf2f(unsigned short s) {
  return __uint_as_float((unsigned)s << 16);
}

/* MODE 0 = FULL (real math); MODE 1 = NOEPI (epilogue ablated, MFMA+LDS live) */
template<int MODE>
__global__ __launch_bounds__(512, 4) void pair_kernel(
    const float* __restrict__ emb, const int* __restrict__ idx,
    float* __restrict__ pt, float* __restrict__ ps) {
  /* triangular fold within each rep: (u in [0,32), bx in [0,65)) */
  const int rep = blockIdx.y >> 5;
  const int u   = blockIdx.y & 31;
  const int bx  = blockIdx.x;
  int it, jt;
  if (bx < NT - u) { it = u;          jt = u + bx; }
  else             { it = NT - 1 - u; jt = bx - 1; }

  /* B tile in MFMA fragment-linear order: [mj][half][lr] x 16B chunks */
  __shared__ __align__(16) unsigned short BH[2048];  /* 4KB hi */
  __shared__ __align__(16) unsigned short BL[2048];  /* 4KB lo */
  __shared__ float2 SFJ[TILE];   /* x = sq_j, y = fam_j (None=-2) */
  __shared__ float  SQI[TILE];   /* sq_i */
  __shared__ float  FAI[TILE];   /* fam_i (None=-1) */
  __shared__ float  rT[8], rS[8];

  const int t  = threadIdx.x;
  const int w  = t >> 6;          /* wave 0..7: i-strip w */
  const int l  = t & 63;
  const int lr = l & 15;          /* fragment row/col index */
  const int g  = l >> 4;          /* k-slice group 0..3 */
  const int half = g & 1;         /* dims 0-7 vs 8-15 */

  /* (a) per-row scalars: t<128 -> i-side, 128<=t<256 -> j-side */
  if (t < 256) {
    const int local = t & 127;
    const int row = ((t < 128) ? it : jt) * TILE + local;
    const float4* s4 = (const float4*)(emb + (size_t)row * D);
    float4 a0 = s4[0], a1 = s4[1], a2 = s4[2], a3 = s4[3];
    float v[16];
    v[0]=a0.x; v[1]=a0.y; v[2]=a0.z; v[3]=a0.w;
    v[4]=a1.x; v[5]=a1.y; v[6]=a1.z; v[7]=a1.w;
    v[8]=a2.x; v[9]=a2.y; v[10]=a2.z; v[11]=a2.w;
    v[12]=a3.x; v[13]=a3.y; v[14]=a3.z; v[15]=a3.w;
    float ss = v[0] * v[0];
#pragma unroll
    for (int k = 1; k < 16; ++k) ss = fmaf(v[k], v[k], ss);
    const int f = FAM_LUT[idx[row] & 63];
    if (t < 128) { SQI[local] = ss; FAI[local] = (f >= 0) ? (float)f : -1.0f; }
    else         { SFJ[local] = make_float2(ss, (f >= 0) ? (float)f : -2.0f); }
  }

  /* (b) B-tile hi/lo conversion + staging: t<256, one 16B chunk each */
  if (t < 256) {
    const int mjs = t >> 5, hs = (t >> 4) & 1, lrs = t & 15;
    const int row = jt * TILE + mjs * 16 + lrs;
    const float4* s4 = (const float4*)(emb + (size_t)row * D + hs * 8);
    float4 b0 = s4[0], b1 = s4[1];
    float vb[8];
    vb[0]=b0.x; vb[1]=b0.y; vb[2]=b0.z; vb[3]=b0.w;
    vb[4]=b1.x; vb[5]=b1.y; vb[6]=b1.z; vb[7]=b1.w;
    unsigned short h8[8], l8[8];
#pragma unroll
    for (int k = 0; k < 8; ++k) {
      h8[k] = f2bf(vb[k]);
      l8[k] = f2bf(vb[k] - bf2f(h8[k]));
    }
    *(bf16x8*)(BH + t * 8) = *(bf16x8*)h8;
    *(bf16x8*)(BL + t * 8) = *(bf16x8*)l8;
  }

  /* (c) A fragment ([hi|lo] along K=32): direct from raw f32 */
  const int arow = it * TILE + w * 16 + lr;
  const float4* a4 = (const float4*)(emb + (size_t)arow * D + half * 8);
  float4 c0 = a4[0], c1 = a4[1];
  float va[8];
  va[0]=c0.x; va[1]=c0.y; va[2]=c0.z; va[3]=c0.w;
  va[4]=c1.x; va[5]=c1.y; va[6]=c1.z; va[7]=c1.w;
  unsigned short f8[8];
#pragma unroll
  for (int k = 0; k < 8; ++k) {
    const unsigned short h = f2bf(va[k]);
    f8[k] = (g < 2) ? h : f2bf(va[k] - bf2f(h));
  }
  const bf16x8 afrag = *(bf16x8*)f8;

  __syncthreads();

  float sqi[4], fai[4];
#pragma unroll
  for (int r = 0; r < 4; ++r) {
    sqi[r] = SQI[w * 16 + g * 4 + r];   /* C/D row = g*4+r */
    fai[r] = FAI[w * 16 + g * 4 + r];
  }

  const int bofs = (half * 16 + lr) * 8;   /* ushort offset within an mj-group */
  float accT = 0.0f, accS = 0.0f;
#pragma unroll 2
  for (int mj = 0; mj < 8; ++mj) {
    const bf16x8 bhi = *(const bf16x8*)(BH + mj * 256 + bofs);
    const bf16x8 blo = *(const bf16x8*)(BL + mj * 256 + bofs);
    const float2 sfj = SFJ[mj * 16 + lr];            /* C/D col = lr */
    f32x4 acc = {0.0f, 0.0f, 0.0f, 0.0f};
    acc = __builtin_amdgcn_mfma_f32_16x16x32_bf16(afrag, blo, acc, 0, 0, 0);
    acc = __builtin_amdgcn_mfma_f32_16x16x32_bf16(afrag, bhi, acc, 0, 0, 0);
    if (MODE == 0) {
#pragma unroll
      for (int r = 0; r < 4; ++r) {
        float d2 = fmaf(-2.0f, acc[r], sqi[r] + sfj.x);
        d2 = fmaxf(d2, 0.0f);
        const float dist = SQRTF(d2);
        accT += dist;
        accS += (fai[r] == sfj.y) ? dist : 0.0f;
      }
    } else {
      /* NOEPI ablation: keep MFMA + LDS reads live, drop max/sqrt/select */
#pragma unroll
      for (int r = 0; r < 4; ++r) {
        accT += acc[r] + sqi[r];
        accS += sfj.x + fai[r] + sfj.y;
      }
    }
  }

  /* block reduction */
#pragma unroll
  for (int off = 32; off > 0; off >>= 1) {
    accT += __shfl_down(accT, off);
    accS += __shfl_down(accS, off);
  }
  if (l == 0) { rT[w] = accT; rS[w] = accS; }
  __syncthreads();
  if (t == 0) {
    float sT = 0.0f, sS = 0.0f;
#pragma unroll
    for (int k = 0; k < 8; ++k) { sT += rT[k]; sS += rS[k]; }
    const float wgt = (it == jt) ? 1.0f : 2.0f;
    const int bid = rep * NBLK + u * 65 + bx;
    pt[bid] = wgt * sT;
    ps[bid] = wgt * sS;
  }
}

__global__ __launch_bounds__(512) void final_kernel(
    const float* __restrict__ pt, const float* __restrict__ ps,
    const int* __restrict__ idx, float* __restrict__ out) {
  const int t = threadIdx.x, w = t >> 6, l = t & 63;
  __shared__ float  HW[8][8];    /* per-wave family counts */
  __shared__ double rTd[8], rSd[8];

  /* ballot histogram: no atomics */
  float myCnt = 0.0f;            /* lane f (<6) counts family f */
#pragma unroll
  for (int rr = 0; rr < 16; ++rr) {
    const int f = FAM_LUT[idx[rr * 512 + t] & 63];
#pragma unroll
    for (int fam = 0; fam < 6; ++fam) {
      const unsigned long long mk = __ballot(f == fam);
      if (l == fam) myCnt += (float)__popcll(mk);
    }
  }
  if (l < 8) HW[w][l] = (l < 6) ? myCnt : 0.0f;

  double sT = 0.0, sS = 0.0;
  for (int k = t; k < NBLK; k += 512) { sT += (double)pt[k]; sS += (double)ps[k]; }
#pragma unroll
  for (int off = 32; off > 0; off >>= 1) {
    sT += __shfl_down(sT, off);
    sS += __shfl_down(sS, off);
  }
  if (l == 0) { rTd[w] = sT; rSd[w] = sS; }
  __syncthreads();
  if (t == 0) {
    double tot = 0.0, sam = 0.0;
#pragma unroll
    for (int k = 0; k < 8; ++k) { tot += rTd[k]; sam += rSd[k]; }
    double same_sum = 0.0;
    for (int f = 0; f < 6; ++f) {
      double c = 0.0;
      for (int k = 0; k < 8; ++k) c += (double)HW[k][f];
      same_sum += c * c;
    }
    const double total  = (double)N_ROWS * (double)N_ROWS;
    const double same_d = sam / (same_sum + 1e-10);
    const double diff_d = (tot - sam) / (total - same_sum + 1e-10);
    double loss = same_d - 0.5 * diff_d + 1.0;
    out[0] = (float)(loss > 0.0 ? loss : 0.0);
  }
}

extern "C" void kernel_launch(void* const* d_in, const int* in_sizes, int n_in,
                              void* d_out, int out_size, void* d_ws, size_t ws_size,
                              hipStream_t stream) {
  const float* emb = (const float*)d_in[0];
  const int*   idx = (const int*)d_in[1];
  char* ws = (char*)d_ws;
  float* pt  = (float*)(ws + OFF_PT);
  float* ps  = (float*)(ws + OFF_PS);
  float* ptA = (float*)(ws + OFF_PTA);
  float* psA = (float*)(ws + OFF_PSA);
  float* ptB = (float*)(ws + OFF_PTB);
  float* psB = (float*)(ws + OFF_PSB);

  /* real work (rep slice 0 feeds final) */
  pair_kernel<0><<<dim3(65, 32), dim3(512), 0, stream>>>(emb, idx, pt, ps);
  /* DIAGNOSTIC dispatches (outputs unused by final; durations > 39us fills
     so they surface in top-5 with full PMC counters):
     A = 4 reps of the real kernel; B = 6 reps with epilogue ablated */
  pair_kernel<0><<<dim3(65, 128), dim3(512), 0, stream>>>(emb, idx, ptA, psA);
  pair_kernel<1><<<dim3(65, 192), dim3(512), 0, stream>>>(emb, idx, ptB, psB);
  final_kernel<<<dim3(1), dim3(512), 0, stream>>>(pt, ps, idx, (float*)d_out);
}

// Round 10
// 26.403 us; speedup vs baseline: 4.7951x; 4.7951x over previous
//
#include <hip/hip_runtime.h>
#include <math.h>

#define N_ROWS 8192
#define D 16
#define TILE 128
#define NT 64            /* 8192/128 */
#define NBLK 2080        /* NT*(NT+1)/2 upper-tri tiles = 32*65 */

/* workspace layout (bytes) */
#define OFF_PT    0          /* float  pt[2080] */
#define OFF_PS    16384      /* float  ps[2080] */
#define OFF_AP    32768      /* ushort aP [8192*32]  512KB  A operand: [-2a_hi(16) | -2a_lo(0..11) | 1, sq_hi, sq_lo, -2a_lo15] */
#define OFF_B1    557056     /* ushort b1 [8192*32]  512KB  B var1:   [b_hi(16) | b_hi(0..11) | sq_hi, 1, 1, b_hi15] */
#define OFF_B2    1081344    /* ushort b2 [8192*32]  512KB  B var2:   [b_lo(16) | b_lo(0..11) | sq_lo, 0, 0, b_lo15] */
#define OFF_FOH   1605632    /* ushort foh[8192*8]   128KB  one-hot family (None = all-zero) */

typedef short  bf16x8 __attribute__((ext_vector_type(8)));
typedef float  f32x4  __attribute__((ext_vector_type(4)));

#if __has_builtin(__builtin_amdgcn_sqrtf)
#define SQRTF(x) __builtin_amdgcn_sqrtf(x)
#else
#define SQRTF(x) sqrtf(x)
#endif

/* codon index -> biosynthetic family id (K resolves to aspartate; '*' -> -1)
   families: 0=glutamate 1=aspartate 2=serine 3=pyruvate 4=aromatic 5=histidine */
__device__ __constant__ signed char FAM_LUT[64] = {
  4,4,3,3, 3,3,3,3,   /* UUU..CUG: F F L L L L L L */
  1,1,1,1, 3,3,3,3,   /* AUU..GUG: I I I M V V V V */
  2,2,2,2, 0,0,0,0,   /* UCU..CCG: S S S S P P P P */
  1,1,1,1, 3,3,3,3,   /* ACU..GCG: T T T T A A A A */
  4,4,-1,-1, 5,5,0,0, /* UAU..CAG: Y Y * * H H Q Q */
  1,1,1,1, 1,1,0,0,   /* AAU..GAG: N N K K D D E E */
  2,2,-1,4, 0,0,0,0,  /* UGU..CGG: C C * W R R R R */
  2,2,0,0, 2,2,2,2    /* AGU..GGG: S S R R G G G G */
};

__device__ __forceinline__ unsigned short f2bf(float f) {   /* RNE, finite inputs */
  unsigned u = __float_as_uint(f);
  u += 0x7fffu + ((u >> 16) & 1u);
  return (unsigned short)(u >> 16);
}
__device__ __forceinline__ float bf2f(unsigned short s) {
  return __uint_as_float((unsigned)s << 16);
}

/* prep: each thread packs one row's MFMA operands (done ONCE, not per tile) */
__global__ __launch_bounds__(256) void prep_kernel(
    const float* __restrict__ emb, const int* __restrict__ idx,
    unsigned short* __restrict__ aP, unsigned short* __restrict__ b1,
    unsigned short* __restrict__ b2, unsigned short* __restrict__ foh) {
  const int i = blockIdx.x * 256 + threadIdx.x;
  const float4* src = (const float4*)(emb + (size_t)i * D);
  float v[16];
  float4 a0 = src[0], a1 = src[1], a2 = src[2], a3 = src[3];
  v[0]=a0.x; v[1]=a0.y; v[2]=a0.z; v[3]=a0.w;
  v[4]=a1.x; v[5]=a1.y; v[6]=a1.z; v[7]=a1.w;
  v[8]=a2.x; v[9]=a2.y; v[10]=a2.z; v[11]=a2.w;
  v[12]=a3.x; v[13]=a3.y; v[14]=a3.z; v[15]=a3.w;

  float sq = v[0] * v[0];
#pragma unroll
  for (int k = 1; k < 16; ++k) sq = fmaf(v[k], v[k], sq);
  const unsigned short sqh = f2bf(sq);
  const unsigned short sql = f2bf(sq - bf2f(sqh));
  const unsigned short ONE = 0x3F80;

  unsigned short ah[16], al[16], bh[16], bl[16];
#pragma unroll
  for (int k = 0; k < 16; ++k) {
    bh[k] = f2bf(v[k]);
    bl[k] = f2bf(v[k] - bf2f(bh[k]));
    const float s = -2.0f * v[k];          /* exact scaling */
    ah[k] = f2bf(s);
    al[k] = f2bf(s - bf2f(ah[k]));
  }

  unsigned short A[32], B1[32], B2[32];
#pragma unroll
  for (int k = 0; k < 16; ++k) { A[k] = ah[k]; B1[k] = bh[k]; B2[k] = bl[k]; }
#pragma unroll
  for (int k = 0; k < 12; ++k) { A[16+k] = al[k]; B1[16+k] = bh[k]; B2[16+k] = bl[k]; }
  /* slot 28: 1 * (sqj_hi + sqj_lo);  29/30: sqi_hi/lo * 1;  31: dim15 lo-residual */
  A[28] = ONE;  A[29] = sqh;  A[30] = sql;  A[31] = al[15];
  B1[28] = sqh; B1[29] = ONE; B1[30] = ONE; B1[31] = bh[15];
  B2[28] = sql; B2[29] = 0;   B2[30] = 0;   B2[31] = bl[15];

#pragma unroll
  for (int c = 0; c < 4; ++c) {
    *(bf16x8*)(aP + (size_t)i * 32 + c * 8) = *(bf16x8*)&A[c * 8];
    *(bf16x8*)(b1 + (size_t)i * 32 + c * 8) = *(bf16x8*)&B1[c * 8];
    *(bf16x8*)(b2 + (size_t)i * 32 + c * 8) = *(bf16x8*)&B2[c * 8];
  }
  const int f = FAM_LUT[idx[i] & 63];
  unsigned short oh[8];
#pragma unroll
  for (int k = 0; k < 8; ++k) oh[k] = (f == k) ? ONE : (unsigned short)0;
  *(bf16x8*)(foh + (size_t)i * 8) = *(bf16x8*)oh;
}

__global__ __launch_bounds__(512, 4) void pair_kernel(
    const unsigned short* __restrict__ aP, const unsigned short* __restrict__ b1g,
    const unsigned short* __restrict__ b2g, const unsigned short* __restrict__ fohg,
    float* __restrict__ pt, float* __restrict__ ps) {
  /* triangular fold: grid (65,32) -> every block a live upper-tri 128x128 tile */
  const int u = blockIdx.y, bx = blockIdx.x;
  int it, jt;
  if (bx < NT - u) { it = u;          jt = u + bx; }
  else             { it = NT - 1 - u; jt = bx - 1; }

  __shared__ __align__(16) unsigned short LB1[4096];  /* 8KB: j-tile B1 [row][32] */
  __shared__ __align__(16) unsigned short LB2[4096];  /* 8KB: j-tile B2 */
  __shared__ __align__(16) unsigned short LFB[1024];  /* 2KB: j-tile one-hot */
  __shared__ __align__(16) unsigned short LZ[8];      /* 16B zeros */
  __shared__ float rT[8], rS[8];

  const int t  = threadIdx.x;
  const int w  = t >> 6;          /* wave 0..7: i-strip w */
  const int l  = t & 63;
  const int lr = l & 15;          /* fragment row/col index */
  const int g  = l >> 4;          /* k-slice group 0..3 */

  /* stage j-tile: thread t owns chunk (row=t>>2, c=t&3) of B1 and B2 */
  {
    const int rl = t >> 2, c = t & 3;
    const size_t gb = (size_t)(jt * TILE + rl) * 32 + c * 8;
    *(bf16x8*)(LB1 + rl * 32 + c * 8) = *(const bf16x8*)(b1g + gb);
    *(bf16x8*)(LB2 + rl * 32 + c * 8) = *(const bf16x8*)(b2g + gb);
    if (t < TILE) *(bf16x8*)(LFB + t * 8) =
        *(const bf16x8*)(fohg + (size_t)(jt * TILE + t) * 8);
    if (t == 128) { bf16x8 z = {0,0,0,0,0,0,0,0}; *(bf16x8*)LZ = z; }
  }

  /* A fragments (packed operand + one-hot), straight loads */
  const int arow = it * TILE + w * 16 + lr;
  const bf16x8 afrag = *(const bf16x8*)(aP + (size_t)arow * 32 + g * 8);
  bf16x8 afrag3;
  if (g == 0) afrag3 = *(const bf16x8*)(fohg + (size_t)arow * 8);
  else        { bf16x8 z = {0,0,0,0,0,0,0,0}; afrag3 = z; }

  __syncthreads();

  const unsigned short* p3 = (g == 0) ? (LFB + lr * 8) : LZ;
  const int step3 = (g == 0) ? 128 : 0;     /* ushorts per mj (16 rows x 8) */
  const int boff  = lr * 32 + g * 8;
  const f32x4 zf = {0.0f, 0.0f, 0.0f, 0.0f};
  float accT = 0.0f, accS = 0.0f;
#pragma unroll 2
  for (int mj = 0; mj < 8; ++mj) {
    const bf16x8 f1 = *(const bf16x8*)(LB1 + mj * 512 + boff);
    const bf16x8 f2 = *(const bf16x8*)(LB2 + mj * 512 + boff);
    const bf16x8 f3 = *(const bf16x8*)(p3 + mj * step3);
    /* acc = sqi + sqj - 2*dot = d2 (sq folded into K-slots); msk in {0,1} exact */
    f32x4 acc = __builtin_amdgcn_mfma_f32_16x16x32_bf16(afrag, f1, zf, 0, 0, 0);
    acc = __builtin_amdgcn_mfma_f32_16x16x32_bf16(afrag, f2, acc, 0, 0, 0);
    const f32x4 msk = __builtin_amdgcn_mfma_f32_16x16x32_bf16(afrag3, f3, zf, 0, 0, 0);
#pragma unroll
    for (int r = 0; r < 4; ++r) {
      const float d2   = fmaxf(acc[r], 0.0f);
      const float dist = SQRTF(d2);
      accT += dist;
      accS = fmaf(msk[r], dist, accS);
    }
  }

  /* block reduction (fp32 partials ~1e5, fine) */
#pragma unroll
  for (int off = 32; off > 0; off >>= 1) {
    accT += __shfl_down(accT, off);
    accS += __shfl_down(accS, off);
  }
  if (l == 0) { rT[w] = accT; rS[w] = accS; }
  __syncthreads();
  if (t == 0) {
    float sT = 0.0f, sS = 0.0f;
#pragma unroll
    for (int k = 0; k < 8; ++k) { sT += rT[k]; sS += rS[k]; }
    const float wgt = (it == jt) ? 1.0f : 2.0f;
    const int bid = blockIdx.y * gridDim.x + blockIdx.x;
    pt[bid] = wgt * sT;
    ps[bid] = wgt * sS;
  }
}

__global__ __launch_bounds__(1024) void final_kernel(
    const float* __restrict__ pt, const float* __restrict__ ps,
    const int* __restrict__ idx, float* __restrict__ out) {
  const int t = threadIdx.x, w = t >> 6, l = t & 63;
  __shared__ float  HW[16][8];
  __shared__ double rTd[16], rSd[16];

  /* ballot histogram: 8 idx per thread via 2 coalesced int4 loads */
  const int4* p4 = (const int4*)idx;
  const int4 va = p4[t], vb = p4[t + 1024];
  int vals[8] = {va.x, va.y, va.z, va.w, vb.x, vb.y, vb.z, vb.w};
  float myCnt = 0.0f;            /* lane f (<6) counts family f */
#pragma unroll
  for (int rr = 0; rr < 8; ++rr) {
    const int f = FAM_LUT[vals[rr] & 63];
#pragma unroll
    for (int fam = 0; fam < 6; ++fam) {
      const unsigned long long mk = __ballot(f == fam);
      if (l == fam) myCnt += (float)__popcll(mk);
    }
  }
  if (l < 8) HW[w][l] = (l < 6) ? myCnt : 0.0f;

  double sT = 0.0, sS = 0.0;
  for (int k = t; k < NBLK; k += 1024) { sT += (double)pt[k]; sS += (double)ps[k]; }
#pragma unroll
  for (int off = 32; off > 0; off >>= 1) {
    sT += __shfl_down(sT, off);
    sS += __shfl_down(sS, off);
  }
  if (l == 0) { rTd[w] = sT; rSd[w] = sS; }
  __syncthreads();
  if (t == 0) {
    double tot = 0.0, sam = 0.0;
#pragma unroll
    for (int k = 0; k < 16; ++k) { tot += rTd[k]; sam += rSd[k]; }
    double same_sum = 0.0;
    for (int f = 0; f < 6; ++f) {
      double c = 0.0;
      for (int k = 0; k < 16; ++k) c += (double)HW[k][f];
      same_sum += c * c;
    }
    const double total  = (double)N_ROWS * (double)N_ROWS;
    const double same_d = sam / (same_sum + 1e-10);
    const double diff_d = (tot - sam) / (total - same_sum + 1e-10);
    double loss = same_d - 0.5 * diff_d + 1.0;
    out[0] = (float)(loss > 0.0 ? loss : 0.0);
  }
}

extern "C" void kernel_launch(void* const* d_in, const int* in_sizes, int n_in,
                              void* d_out, int out_size, void* d_ws, size_t ws_size,
                              hipStream_t stream) {
  const float* emb = (const float*)d_in[0];
  const int*   idx = (const int*)d_in[1];
  char* ws = (char*)d_ws;
  float*          pt  = (float*)(ws + OFF_PT);
  float*          ps  = (float*)(ws + OFF_PS);
  unsigned short* aP  = (unsigned short*)(ws + OFF_AP);
  unsigned short* b1  = (unsigned short*)(ws + OFF_B1);
  unsigned short* b2  = (unsigned short*)(ws + OFF_B2);
  unsigned short* foh = (unsigned short*)(ws + OFF_FOH);

  prep_kernel<<<dim3(N_ROWS / 256), dim3(256), 0, stream>>>(emb, idx, aP, b1, b2, foh);
  pair_kernel<<<dim3(NT + 1, NT / 2), dim3(512), 0, stream>>>(aP, b1, b2, foh, pt, ps);
  final_kernel<<<dim3(1), dim3(1024), 0, stream>>>(pt, ps, idx, (float*)d_out);
}

// Round 11
// 25.854 us; speedup vs baseline: 4.8969x; 1.0212x over previous
//
#include <hip/hip_runtime.h>
#include <math.h>

#define N_ROWS 8192
#define D 16
#define TILE 128
#define NT 64            /* 8192/128 */
#define NBLK 2080        /* NT*(NT+1)/2 upper-tri tiles = 32*65 */

/* workspace layout (bytes) */
#define OFF_PT   0            /* float pt[2080] */
#define OFF_PS   16384        /* float ps[2080] */

typedef short  bf16x8 __attribute__((ext_vector_type(8)));
typedef float  f32x4  __attribute__((ext_vector_type(4)));

#if __has_builtin(__builtin_amdgcn_sqrtf)
#define SQRTF(x) __builtin_amdgcn_sqrtf(x)
#else
#define SQRTF(x) sqrtf(x)
#endif

#define BF_ONE ((unsigned short)0x3F80)

/* codon index -> biosynthetic family id (K resolves to aspartate; '*' -> -1)
   families: 0=glutamate 1=aspartate 2=serine 3=pyruvate 4=aromatic 5=histidine */
__device__ __constant__ signed char FAM_LUT[64] = {
  4,4,3,3, 3,3,3,3,   /* UUU..CUG: F F L L L L L L */
  1,1,1,1, 3,3,3,3,   /* AUU..GUG: I I I M V V V V */
  2,2,2,2, 0,0,0,0,   /* UCU..CCG: S S S S P P P P */
  1,1,1,1, 3,3,3,3,   /* ACU..GCG: T T T T A A A A */
  4,4,-1,-1, 5,5,0,0, /* UAU..CAG: Y Y * * H H Q Q */
  1,1,1,1, 1,1,0,0,   /* AAU..GAG: N N K K D D E E */
  2,2,-1,4, 0,0,0,0,  /* UGU..CGG: C C * W R R R R */
  2,2,0,0, 2,2,2,2    /* AGU..GGG: S S R R G G G G */
};

__device__ __forceinline__ unsigned short f2bf(float f) {   /* RNE, finite inputs */
  unsigned u = __float_as_uint(f);
  u += 0x7fffu + ((u >> 16) & 1u);
  return (unsigned short)(u >> 16);
}
__device__ __forceinline__ float bf2f(unsigned short s) {
  return __uint_as_float((unsigned)s << 16);
}

/* Operand layout (K=32 slots), sq folded into slots 28..30:
   A : [-2a_hi(0..15) | -2a_lo(0..11) | ONE, sqi_hi, sqi_lo, -2a_lo15]
   B1: [ b_hi(0..15)  |  b_hi(0..11)  | sqj_hi, ONE, ONE,  b_hi15]
   B2: [ b_lo(0..15)  |  b_lo(0..11)  | sqj_lo, 0,   0,    b_lo15]
   => acc(A,B1)+acc(A,B2) = sqi + sqj - 2*dot = d2 */
__global__ __launch_bounds__(512, 4) void pair_kernel(
    const float* __restrict__ emb, const int* __restrict__ idx,
    float* __restrict__ pt, float* __restrict__ ps) {
  /* triangular fold: grid (65,32) -> every block a live upper-tri 128x128 tile */
  const int u = blockIdx.y, bx = blockIdx.x;
  int it, jt;
  if (bx < NT - u) { it = u;          jt = u + bx; }
  else             { it = NT - 1 - u; jt = bx - 1; }

  __shared__ __align__(16) unsigned short LB1[4096];  /* 8KB: j-tile B1 [row][32] */
  __shared__ __align__(16) unsigned short LB2[4096];  /* 8KB: j-tile B2 */
  __shared__ __align__(16) unsigned short LFB[1024];  /* 2KB: j one-hot */
  __shared__ __align__(16) unsigned short LFA[1024];  /* 2KB: i one-hot */
  __shared__ __align__(16) unsigned short LZ[8];      /* 16B zeros */
  __shared__ float SQIF[TILE], SQJF[TILE];
  __shared__ float rT[8], rS[8];

  const int t  = threadIdx.x;
  const int w  = t >> 6;          /* wave 0..7: i-strip w */
  const int l  = t & 63;
  const int lr = l & 15;          /* fragment row/col index */
  const int g  = l >> 4;          /* k-slice group 0..3 */

  /* (a) per-row sq + one-hot: t<128 i-side, 128<=t<256 j-side */
  if (t < 256) {
    const int local = t & 127;
    const int row = ((t < 128) ? it : jt) * TILE + local;
    const float4* s4 = (const float4*)(emb + (size_t)row * D);
    float4 a0 = s4[0], a1 = s4[1], a2 = s4[2], a3 = s4[3];
    float v[16];
    v[0]=a0.x; v[1]=a0.y; v[2]=a0.z; v[3]=a0.w;
    v[4]=a1.x; v[5]=a1.y; v[6]=a1.z; v[7]=a1.w;
    v[8]=a2.x; v[9]=a2.y; v[10]=a2.z; v[11]=a2.w;
    v[12]=a3.x; v[13]=a3.y; v[14]=a3.z; v[15]=a3.w;
    float ss = v[0] * v[0];
#pragma unroll
    for (int k = 1; k < 16; ++k) ss = fmaf(v[k], v[k], ss);
    const int f = FAM_LUT[idx[row] & 63];
    unsigned short oh[8];
#pragma unroll
    for (int k = 0; k < 8; ++k) oh[k] = (f == k) ? BF_ONE : (unsigned short)0;
    if (t < 128) { SQIF[local] = ss; *(bf16x8*)(LFA + local * 8) = *(bf16x8*)oh; }
    else         { SQJF[local] = ss; *(bf16x8*)(LFB + local * 8) = *(bf16x8*)oh; }
  } else if (t == 256) {
    bf16x8 z = {0,0,0,0,0,0,0,0};
    *(bf16x8*)LZ = z;
  }
  __syncthreads();   /* bar1: SQIF/SQJF/LFA visible */

  /* (b) pack B1/B2 into LDS: t<256, thread owns (row rl, half h) — 8 dims */
  if (t < 256) {
    const int rl = t >> 1, h = t & 1;
    const int row = jt * TILE + rl;
    const float4* s4 = (const float4*)(emb + (size_t)row * D + h * 8);
    float4 b0 = s4[0], b1v = s4[1];
    float v[8];
    v[0]=b0.x; v[1]=b0.y; v[2]=b0.z; v[3]=b0.w;
    v[4]=b1v.x; v[5]=b1v.y; v[6]=b1v.z; v[7]=b1v.w;
    unsigned short bh[8], bl[8];
#pragma unroll
    for (int k = 0; k < 8; ++k) {
      bh[k] = f2bf(v[k]);
      bl[k] = f2bf(v[k] - bf2f(bh[k]));
    }
    unsigned short* d1 = LB1 + rl * 32;
    unsigned short* d2 = LB2 + rl * 32;
    if (h == 0) {            /* dims 0-7: slots 0-7 and 16-23 */
      *(bf16x8*)(d1 + 0)  = *(bf16x8*)bh;
      *(bf16x8*)(d1 + 16) = *(bf16x8*)bh;
      *(bf16x8*)(d2 + 0)  = *(bf16x8*)bl;
      *(bf16x8*)(d2 + 16) = *(bf16x8*)bl;
    } else {                 /* dims 8-15: slots 8-15 and 24-31 (w/ sq fold) */
      *(bf16x8*)(d1 + 8) = *(bf16x8*)bh;
      *(bf16x8*)(d2 + 8) = *(bf16x8*)bl;
      const float sq = SQJF[rl];
      const unsigned short sqh = f2bf(sq);
      const unsigned short sql = f2bf(sq - bf2f(sqh));
      unsigned short c3h[8] = {bh[0], bh[1], bh[2], bh[3], sqh, BF_ONE, BF_ONE, bh[7]};
      unsigned short c3l[8] = {bl[0], bl[1], bl[2], bl[3], sql, 0, 0, bl[7]};
      *(bf16x8*)(d1 + 24) = *(bf16x8*)c3h;
      *(bf16x8*)(d2 + 24) = *(bf16x8*)c3l;
    }
  }

  /* (c) A fragment, branch-free hi/lo select; g==3 gets the sq-fold slots */
  const int arow = it * TILE + w * 16 + lr;
  const float4* a4 = (const float4*)(emb + (size_t)arow * D + (g & 1) * 8);
  float4 c0 = a4[0], c1 = a4[1];
  float va[8];
  va[0]=c0.x; va[1]=c0.y; va[2]=c0.z; va[3]=c0.w;
  va[4]=c1.x; va[5]=c1.y; va[6]=c1.z; va[7]=c1.w;
  unsigned short f8[8];
#pragma unroll
  for (int k = 0; k < 8; ++k) {
    const float sv = -2.0f * va[k];               /* exact scaling */
    const unsigned short h  = f2bf(sv);
    const unsigned short lo = f2bf(sv - bf2f(h));
    f8[k] = (g < 2) ? h : lo;
  }
  if (g == 3) {
    const float sq = SQIF[w * 16 + lr];
    const unsigned short sqh = f2bf(sq);
    f8[4] = BF_ONE;
    f8[5] = sqh;
    f8[6] = f2bf(sq - bf2f(sqh));
  }
  const bf16x8 afrag = *(bf16x8*)f8;
  bf16x8 afrag3;
  if (g == 0) afrag3 = *(const bf16x8*)(LFA + (w * 16 + lr) * 8);
  else        { bf16x8 z = {0,0,0,0,0,0,0,0}; afrag3 = z; }

  __syncthreads();   /* bar2: LB1/LB2/LFB visible */

  const unsigned short* p3 = (g == 0) ? (LFB + lr * 8) : LZ;
  const int step3 = (g == 0) ? 128 : 0;     /* ushorts per mj (16 rows x 8) */
  const int boff  = lr * 32 + g * 8;
  const f32x4 zf = {0.0f, 0.0f, 0.0f, 0.0f};
  float accT = 0.0f, accS = 0.0f;
#pragma unroll 2
  for (int mj = 0; mj < 8; ++mj) {
    const bf16x8 f1 = *(const bf16x8*)(LB1 + mj * 512 + boff);
    const bf16x8 f2 = *(const bf16x8*)(LB2 + mj * 512 + boff);
    const bf16x8 f3 = *(const bf16x8*)(p3 + mj * step3);
    /* acc = d2 directly (sq folded); msk in {0,1} exact */
    f32x4 acc = __builtin_amdgcn_mfma_f32_16x16x32_bf16(afrag, f1, zf, 0, 0, 0);
    acc = __builtin_amdgcn_mfma_f32_16x16x32_bf16(afrag, f2, acc, 0, 0, 0);
    const f32x4 msk = __builtin_amdgcn_mfma_f32_16x16x32_bf16(afrag3, f3, zf, 0, 0, 0);
#pragma unroll
    for (int r = 0; r < 4; ++r) {
      const float d2   = fmaxf(acc[r], 0.0f);
      const float dist = SQRTF(d2);
      accT += dist;
      accS = fmaf(msk[r], dist, accS);
    }
  }

  /* block reduction (fp32 partials ~1e5, fine) */
#pragma unroll
  for (int off = 32; off > 0; off >>= 1) {
    accT += __shfl_down(accT, off);
    accS += __shfl_down(accS, off);
  }
  if (l == 0) { rT[w] = accT; rS[w] = accS; }
  __syncthreads();
  if (t == 0) {
    float sT = 0.0f, sS = 0.0f;
#pragma unroll
    for (int k = 0; k < 8; ++k) { sT += rT[k]; sS += rS[k]; }
    const float wgt = (it == jt) ? 1.0f : 2.0f;
    const int bid = blockIdx.y * gridDim.x + blockIdx.x;
    pt[bid] = wgt * sT;
    ps[bid] = wgt * sS;
  }
}

__global__ __launch_bounds__(1024) void final_kernel(
    const float* __restrict__ pt, const float* __restrict__ ps,
    const int* __restrict__ idx, float* __restrict__ out) {
  const int t = threadIdx.x, w = t >> 6, l = t & 63;
  __shared__ float  HW[16][8];
  __shared__ double rTd[16], rSd[16];

  /* ballot histogram: 8 idx per thread via 2 coalesced int4 loads */
  const int4* p4 = (const int4*)idx;
  const int4 va = p4[t], vb = p4[t + 1024];
  int vals[8] = {va.x, va.y, va.z, va.w, vb.x, vb.y, vb.z, vb.w};
  float myCnt = 0.0f;            /* lane f (<6) counts family f */
#pragma unroll
  for (int rr = 0; rr < 8; ++rr) {
    const int f = FAM_LUT[vals[rr] & 63];
#pragma unroll
    for (int fam = 0; fam < 6; ++fam) {
      const unsigned long long mk = __ballot(f == fam);
      if (l == fam) myCnt += (float)__popcll(mk);
    }
  }
  if (l < 8) HW[w][l] = (l < 6) ? myCnt : 0.0f;

  double sT = 0.0, sS = 0.0;
  for (int k = t; k < NBLK; k += 1024) { sT += (double)pt[k]; sS += (double)ps[k]; }
#pragma unroll
  for (int off = 32; off > 0; off >>= 1) {
    sT += __shfl_down(sT, off);
    sS += __shfl_down(sS, off);
  }
  if (l == 0) { rTd[w] = sT; rSd[w] = sS; }
  __syncthreads();
  if (t == 0) {
    double tot = 0.0, sam = 0.0;
#pragma unroll
    for (int k = 0; k < 16; ++k) { tot += rTd[k]; sam += rSd[k]; }
    double same_sum = 0.0;
    for (int f = 0; f < 6; ++f) {
      double c = 0.0;
      for (int k = 0; k < 16; ++k) c += (double)HW[k][f];
      same_sum += c * c;
    }
    const double total  = (double)N_ROWS * (double)N_ROWS;
    const double same_d = sam / (same_sum + 1e-10);
    const double diff_d = (tot - sam) / (total - same_sum + 1e-10);
    double loss = same_d - 0.5 * diff_d + 1.0;
    out[0] = (float)(loss > 0.0 ? loss : 0.0);
  }
}

extern "C" void kernel_launch(void* const* d_in, const int* in_sizes, int n_in,
                              void* d_out, int out_size, void* d_ws, size_t ws_size,
                              hipStream_t stream) {
  const float* emb = (const float*)d_in[0];
  const int*   idx = (const int*)d_in[1];
  char* ws = (char*)d_ws;
  float* pt = (float*)(ws + OFF_PT);
  float* ps = (float*)(ws + OFF_PS);

  pair_kernel<<<dim3(NT + 1, NT / 2), dim3(512), 0, stream>>>(emb, idx, pt, ps);
  final_kernel<<<dim3(1), dim3(1024), 0, stream>>>(pt, ps, idx, (float*)d_out);
}

// Round 12
// 23.637 us; speedup vs baseline: 5.3563x; 1.0938x over previous
//
#include <hip/hip_runtime.h>
#include <math.h>

#define N_ROWS 8192
#define D 16
#define TILE 128
#define NT 64            /* 8192/128 */
#define NBLK 2080        /* NT*(NT+1)/2 upper-tri tiles = 32*65 */

/* workspace layout (bytes) */
#define OFF_PT   0            /* float pt[2080] */
#define OFF_PS   16384        /* float ps[2080] */

typedef short  bf16x8 __attribute__((ext_vector_type(8)));
typedef float  f32x4  __attribute__((ext_vector_type(4)));

#define BF_ONE ((unsigned short)0x3F80)

/* codon index -> biosynthetic family id (K resolves to aspartate; '*' -> -1)
   families: 0=glutamate 1=aspartate 2=serine 3=pyruvate 4=aromatic 5=histidine */
__device__ __constant__ signed char FAM_LUT[64] = {
  4,4,3,3, 3,3,3,3,   /* UUU..CUG: F F L L L L L L */
  1,1,1,1, 3,3,3,3,   /* AUU..GUG: I I I M V V V V */
  2,2,2,2, 0,0,0,0,   /* UCU..CCG: S S S S P P P P */
  1,1,1,1, 3,3,3,3,   /* ACU..GCG: T T T T A A A A */
  4,4,-1,-1, 5,5,0,0, /* UAU..CAG: Y Y * * H H Q Q */
  1,1,1,1, 1,1,0,0,   /* AAU..GAG: N N K K D D E E */
  2,2,-1,4, 0,0,0,0,  /* UGU..CGG: C C * W R R R R */
  2,2,0,0, 2,2,2,2    /* AGU..GGG: S S R R G G G G */
};

__device__ __forceinline__ unsigned short f2bf(float f) {   /* RNE, finite inputs */
  unsigned u = __float_as_uint(f);
  u += 0x7fffu + ((u >> 16) & 1u);
  return (unsigned short)(u >> 16);
}
__device__ __forceinline__ float bf2f(unsigned short s) {
  return __uint_as_float((unsigned)s << 16);
}
__device__ __forceinline__ float sqrt_abs(float x) {   /* 1 VALU + 1 trans, always */
  const float ax = __builtin_fabsf(x);
  float r;
  asm("v_sqrt_f32 %0, %1" : "=v"(r) : "v"(ax));
  return r;
}

/* Operand layout (K=32 slots). Distances are of the bf16-ROUNDED point set:
   sq is computed FROM rounded coords, so diag d2 ~ 0 and d2 >= -1e-4.
   A : [-2a_bf(0..15) | ONE, ONE, sqi_hi, sqi_lo, 0 x4 | 0 x8]
   B : [ b_bf(0..15)  | sqj_hi, sqj_lo, ONE, ONE, 0 x4 | 0 x8]
   => acc = sqi + sqj - 2*dot = d2 directly */
__global__ __launch_bounds__(512, 4) void pair_kernel(
    const float* __restrict__ emb, const int* __restrict__ idx,
    float* __restrict__ pt, float* __restrict__ ps) {
  /* triangular fold: grid (65,32) -> every block a live upper-tri 128x128 tile */
  const int u = blockIdx.y, bx = blockIdx.x;
  int it, jt;
  if (bx < NT - u) { it = u;          jt = u + bx; }
  else             { it = NT - 1 - u; jt = bx - 1; }

  __shared__ __align__(16) unsigned short LB1[4096];  /* 8KB: j-tile B [row][32] */
  __shared__ __align__(16) unsigned short LFB[1024];  /* 2KB: j one-hot */
  __shared__ __align__(16) unsigned short LFA[1024];  /* 2KB: i one-hot */
  __shared__ float SQIF[TILE];                        /* i-row sq (rounded basis) */
  __shared__ float rT[8], rS[8];

  const int t  = threadIdx.x;
  const int w  = t >> 6;          /* wave 0..7: i-strip w */
  const int l  = t & 63;
  const int lr = l & 15;          /* fragment row/col index */
  const int g  = l >> 4;          /* k-slice group 0..3 */

  /* (a) staging: t<128 i-side scalars; 128<=t<256 j-side full B row pack */
  if (t < 256) {
    const int  local = t & 127;
    const bool iside = (t < 128);
    const int  row = (iside ? it : jt) * TILE + local;
    const float4* s4 = (const float4*)(emb + (size_t)row * D);
    float4 a0 = s4[0], a1 = s4[1], a2 = s4[2], a3 = s4[3];
    float v[16];
    v[0]=a0.x; v[1]=a0.y; v[2]=a0.z; v[3]=a0.w;
    v[4]=a1.x; v[5]=a1.y; v[6]=a1.z; v[7]=a1.w;
    v[8]=a2.x; v[9]=a2.y; v[10]=a2.z; v[11]=a2.w;
    v[12]=a3.x; v[13]=a3.y; v[14]=a3.z; v[15]=a3.w;
    unsigned short bh[16];
#pragma unroll
    for (int k = 0; k < 16; ++k) bh[k] = f2bf(v[k]);
    float ss = bf2f(bh[0]) * bf2f(bh[0]);          /* sq of ROUNDED coords */
#pragma unroll
    for (int k = 1; k < 16; ++k) { const float rv = bf2f(bh[k]); ss = fmaf(rv, rv, ss); }
    const int f = FAM_LUT[idx[row] & 63];
    unsigned short oh[8];
#pragma unroll
    for (int k = 0; k < 8; ++k) oh[k] = (f == k) ? BF_ONE : (unsigned short)0;
    if (iside) {
      SQIF[local] = ss;
      *(bf16x8*)(LFA + local * 8) = *(bf16x8*)oh;
    } else {
      const unsigned short sqh = f2bf(ss);
      const unsigned short sql = f2bf(ss - bf2f(sqh));
      unsigned short c2[8] = {sqh, sql, BF_ONE, BF_ONE, 0, 0, 0, 0};
      unsigned short cz[8] = {0, 0, 0, 0, 0, 0, 0, 0};
      unsigned short* d1 = LB1 + local * 32;
      *(bf16x8*)(d1 + 0)  = *(bf16x8*)&bh[0];
      *(bf16x8*)(d1 + 8)  = *(bf16x8*)&bh[8];
      *(bf16x8*)(d1 + 16) = *(bf16x8*)c2;
      *(bf16x8*)(d1 + 24) = *(bf16x8*)cz;
      *(bf16x8*)(LFB + local * 8) = *(bf16x8*)oh;
    }
  }

  /* A fragment part 1 (no LDS dep): -2*a_bf for g<2; overwritten for g>=2 */
  const int arow = it * TILE + w * 16 + lr;
  const float4* a4 = (const float4*)(emb + (size_t)arow * D + (g & 1) * 8);
  float4 c0 = a4[0], c1 = a4[1];
  float va[8];
  va[0]=c0.x; va[1]=c0.y; va[2]=c0.z; va[3]=c0.w;
  va[4]=c1.x; va[5]=c1.y; va[6]=c1.z; va[7]=c1.w;
  unsigned short f8[8];
#pragma unroll
  for (int k = 0; k < 8; ++k) f8[k] = f2bf(-2.0f * va[k]);   /* exact x-2 */

  __syncthreads();   /* SQIF/LFA/LFB/LB1 visible */

  /* A fragment part 2: g==2 carries the sq-fold slots; g==3 zero */
  if (g >= 2) {
#pragma unroll
    for (int k = 0; k < 8; ++k) f8[k] = 0;
    if (g == 2) {
      const float sq = SQIF[w * 16 + lr];
      const unsigned short sqh = f2bf(sq);
      f8[0] = BF_ONE; f8[1] = BF_ONE;
      f8[2] = sqh;    f8[3] = f2bf(sq - bf2f(sqh));
    }
  }
  const bf16x8 afrag = *(bf16x8*)f8;
  bf16x8 afrag3;
  if (g == 0) afrag3 = *(const bf16x8*)(LFA + (w * 16 + lr) * 8);
  else        { bf16x8 z = {0,0,0,0,0,0,0,0}; afrag3 = z; }

  /* hoist B and mask fragments into registers: loop has ZERO memory ops */
  bf16x8 b1f[8], m3[8];
#pragma unroll
  for (int mj = 0; mj < 8; ++mj)
    b1f[mj] = *(const bf16x8*)(LB1 + (mj * 16 + lr) * 32 + g * 8);
  if (g == 0) {
#pragma unroll
    for (int mj = 0; mj < 8; ++mj)
      m3[mj] = *(const bf16x8*)(LFB + (mj * 16 + lr) * 8);
  } else {
    bf16x8 z = {0,0,0,0,0,0,0,0};
#pragma unroll
    for (int mj = 0; mj < 8; ++mj) m3[mj] = z;
  }

  const f32x4 zf = {0.0f, 0.0f, 0.0f, 0.0f};
  float accT = 0.0f, accS = 0.0f;
#pragma unroll
  for (int mj = 0; mj < 8; ++mj) {
    /* acc == d2 (sq folded into K-slots); msk in {0,1} exact */
    const f32x4 acc = __builtin_amdgcn_mfma_f32_16x16x32_bf16(afrag,  b1f[mj], zf, 0, 0, 0);
    const f32x4 msk = __builtin_amdgcn_mfma_f32_16x16x32_bf16(afrag3, m3[mj],  zf, 0, 0, 0);
#pragma unroll
    for (int r = 0; r < 4; ++r) {
      const float dist = sqrt_abs(acc[r]);   /* |d2| >= -1e-4 only */
      accT += dist;
      accS = fmaf(msk[r], dist, accS);
    }
  }

  /* block reduction (fp32 partials ~1e5, fine) */
#pragma unroll
  for (int off = 32; off > 0; off >>= 1) {
    accT += __shfl_down(accT, off);
    accS += __shfl_down(accS, off);
  }
  if (l == 0) { rT[w] = accT; rS[w] = accS; }
  __syncthreads();
  if (t == 0) {
    float sT = 0.0f, sS = 0.0f;
#pragma unroll
    for (int k = 0; k < 8; ++k) { sT += rT[k]; sS += rS[k]; }
    const float wgt = (it == jt) ? 1.0f : 2.0f;
    const int bid = blockIdx.y * gridDim.x + blockIdx.x;
    pt[bid] = wgt * sT;
    ps[bid] = wgt * sS;
  }
}

__global__ __launch_bounds__(1024) void final_kernel(
    const float* __restrict__ pt, const float* __restrict__ ps,
    const int* __restrict__ idx, float* __restrict__ out) {
  const int t = threadIdx.x, w = t >> 6, l = t & 63;
  __shared__ float  HW[16][8];
  __shared__ double rTd[16], rSd[16];

  /* ballot histogram: 8 idx per thread via 2 coalesced int4 loads */
  const int4* p4 = (const int4*)idx;
  const int4 va = p4[t], vb = p4[t + 1024];
  int vals[8] = {va.x, va.y, va.z, va.w, vb.x, vb.y, vb.z, vb.w};
  float myCnt = 0.0f;            /* lane f (<6) counts family f */
#pragma unroll
  for (int rr = 0; rr < 8; ++rr) {
    const int f = FAM_LUT[vals[rr] & 63];
#pragma unroll
    for (int fam = 0; fam < 6; ++fam) {
      const unsigned long long mk = __ballot(f == fam);
      if (l == fam) myCnt += (float)__popcll(mk);
    }
  }
  if (l < 8) HW[w][l] = (l < 6) ? myCnt : 0.0f;

  double sT = 0.0, sS = 0.0;
  for (int k = t; k < NBLK; k += 1024) { sT += (double)pt[k]; sS += (double)ps[k]; }
#pragma unroll
  for (int off = 32; off > 0; off >>= 1) {
    sT += __shfl_down(sT, off);
    sS += __shfl_down(sS, off);
  }
  if (l == 0) { rTd[w] = sT; rSd[w] = sS; }
  __syncthreads();
  if (t == 0) {
    double tot = 0.0, sam = 0.0;
#pragma unroll
    for (int k = 0; k < 16; ++k) { tot += rTd[k]; sam += rSd[k]; }
    double same_sum = 0.0;
    for (int f = 0; f < 6; ++f) {
      double c = 0.0;
      for (int k = 0; k < 16; ++k) c += (double)HW[k][f];
      same_sum += c * c;
    }
    const double total  = (double)N_ROWS * (double)N_ROWS;
    const double same_d = sam / (same_sum + 1e-10);
    const double diff_d = (tot - sam) / (total - same_sum + 1e-10);
    double loss = same_d - 0.5 * diff_d + 1.0;
    out[0] = (float)(loss > 0.0 ? loss : 0.0);
  }
}

extern "C" void kernel_launch(void* const* d_in, const int* in_sizes, int n_in,
                              void* d_out, int out_size, void* d_ws, size_t ws_size,
                              hipStream_t stream) {
  const float* emb = (const float*)d_in[0];
  const int*   idx = (const int*)d_in[1];
  char* ws = (char*)d_ws;
  float* pt = (float*)(ws + OFF_PT);
  float* ps = (float*)(ws + OFF_PS);

  pair_kernel<<<dim3(NT + 1, NT / 2), dim3(512), 0, stream>>>(emb, idx, pt, ps);
  final_kernel<<<dim3(1), dim3(1024), 0, stream>>>(pt, ps, idx, (float*)d_out);
}